// Round 5
// baseline (174.361 us; speedup 1.0000x reference)
//
#include <hip/hip_runtime.h>

#define B_SZ  2
#define N_PTS 16384
#define M_CTR 4096
#define C_FT  32
#define K_NB  32
#define NCH   35   // 3 + C_FT
#define CH_STRIDE (K_NB * M_CTR)   // 131072
#define CELLS 10
#define NCELL (CELLS * CELLS * CELLS)

// 64-bit flag magic: hi word != lo word, so no 32-bit fill pattern
// (poison is pattern:pattern) can ever alias it.
#define FLAG_MAGIC 0x9E3779B97F4A7C15ULL

typedef float vfloat2 __attribute__((ext_vector_type(2)));  // NT-store-able

// ---------------------------------------------------------------------------
// Exact single-rounded f32 ops, opaque to the compiler. v_fma_f32 ONLY where
// the numpy golden fuses (einsum cp accumulation). absmax==0.0 since R6 —
// DO NOT change the math.
// ---------------------------------------------------------------------------
__device__ __forceinline__ float fmul(float a, float b) {
    float r; asm("v_mul_f32 %0, %1, %2" : "=v"(r) : "v"(a), "v"(b)); return r;
}
__device__ __forceinline__ float fadd(float a, float b) {
    float r; asm("v_add_f32 %0, %1, %2" : "=v"(r) : "v"(a), "v"(b)); return r;
}
__device__ __forceinline__ float fsub(float a, float b) {
    float r; asm("v_sub_f32 %0, %1, %2" : "=v"(r) : "v"(a), "v"(b)); return r;
}
__device__ __forceinline__ float ffma(float a, float b, float c) {
    float r; asm("v_fma_f32 %0, %1, %2, %3" : "=v"(r) : "v"(a), "v"(b), "v"(c));
    return r;
}

__device__ __forceinline__ bool bq_valid(float x, float y, float z,
                                         float cx, float cy, float cz,
                                         float c2, float r2) {
    const float p2 = fadd(fadd(fmul(x, x), fmul(y, y)), fmul(z, z));
    const float cp = ffma(cz, z, ffma(cy, y, fmul(cx, x)));
    return fsub(fadd(c2, p2), fmul(2.0f, cp)) < r2;
}

__device__ __forceinline__ int cell_of(float x, float y, float z) {
    int ci = (int)(x * 10.0f); ci = ci < 0 ? 0 : (ci > 9 ? 9 : ci);
    int cj = (int)(y * 10.0f); cj = cj < 0 ? 0 : (cj > 9 ? 9 : cj);
    int ck = (int)(z * 10.0f); ck = ck < 0 ? 0 : (ck > 9 ? 9 : ck);
    return (ck * CELLS + cj) * CELLS + ci;   // x fastest
}

// ---------------------------------------------------------------------------
// R14 prep: transpose + bin + scatter in ONE dispatch, no grid.sync.
// 256 blocks x 1024 threads, __launch_bounds__(1024,4):
//   4096 waves total <= half of chip capacity (8192) and >= 512 block slots
//   -> ALL blocks resident from t0 -> the flag spin cannot deadlock.
// Block j: transposes its own 128 points (2 tiles of 64) -> pf.
//   Blocks 0/1 additionally bin their whole batch (LDS hist + scan),
//   publish starts (plain; consumed after dispatch boundary) and cursor
//   (device-scope atomicExch -> coherence point, readable cross-XCD),
//   threadfence, then release-store FLAG_MAGIC (agent scope).
// All blocks acquire-spin on their scatter-batch's flag (t0 spins,
// __syncthreads broadcasts), then scatter their own 128 points via global
// cursor atomics. Scatter is spread over 256 blocks (R13's mistake was
// serializing it on the 2 bin CUs) and hides under the bin shadow.
// Intra-cell order differs from R2 — irrelevant (bq bitmap restores
// global index order).
// ---------------------------------------------------------------------------
__global__ __launch_bounds__(1024, 4) void prep_kernel(
    const float* __restrict__ points,   // (B,3,N)
    const float* __restrict__ feats,    // (B,C,N)
    int* __restrict__ starts,           // (B,1001)
    int* __restrict__ cursor,           // (B,1000)
    unsigned long long* __restrict__ flags,  // (B)
    float4* __restrict__ binned,        // (B,N) {x,y,z,idx}
    float* __restrict__ pf)             // (B,N,36)
{
    const int j  = blockIdx.x;          // 0..255
    const int t  = threadIdx.x;         // 0..1023
    const int lane = t & 63, wid = t >> 6;
    const int jb = j >> 7;              // batch of my transpose/scatter range
    const int base_n = (j & 127) * 128;

    __shared__ union {
        float tile[64][37];                       // 9.25 KB
        struct { int h[NCELL]; int wsum[16]; } bin;
    } sh;

    // ---- transpose two 64-wide tiles -> pf ------------------------------
#pragma unroll
    for (int half = 0; half < 2; ++half) {
        const int n0 = base_n + half * 64;
        if (half) __syncthreads();      // protect previous tile reads
        for (int i = t; i < NCH * 64; i += 1024) {
            const int r = i >> 6;
            const int c = i & 63;
            float v;
            if (r < 3) v = points[(jb * 3 + r) * N_PTS + n0 + c];
            else       v = feats[(jb * C_FT + (r - 3)) * N_PTS + n0 + c];
            sh.tile[c][r] = v;
        }
        if (t < 64) sh.tile[t][35] = 0.0f;
        __syncthreads();
        float* __restrict__ dst = pf + ((size_t)jb * N_PTS + n0) * 36;
        for (int o = t; o < 64 * 36; o += 1024) {
            const int c = o / 36;
            const int r = o - c * 36;
            dst[o] = sh.tile[c][r];
        }
    }
    __syncthreads();                    // tile use done; bin may reuse LDS

    // ---- blocks 0/1: bin whole batch, publish starts/cursor + flag ------
    if (j < B_SZ) {
        const int b = j;
        for (int c = t; c < NCELL; c += 1024) sh.bin.h[c] = 0;
        __syncthreads();

        const float* __restrict__ px = points + (b * 3 + 0) * N_PTS;
        const float* __restrict__ py = points + (b * 3 + 1) * N_PTS;
        const float* __restrict__ pz = points + (b * 3 + 2) * N_PTS;
#pragma unroll
        for (int i = 0; i < 16; ++i) {
            const int n = t + i * 1024;
            atomicAdd(&sh.bin.h[cell_of(px[n], py[n], pz[n])], 1);
        }
        __syncthreads();

        const int v = (t < NCELL) ? sh.bin.h[t] : 0;
        int incl = v;
        for (int off = 1; off < 64; off <<= 1) {
            const int u = __shfl_up(incl, off);
            if (lane >= off) incl += u;
        }
        if (lane == 63) sh.bin.wsum[wid] = incl;
        __syncthreads();
        if (wid == 0 && lane < 16) {
            const int s = sh.bin.wsum[lane];
            int in2 = s;
            for (int off = 1; off < 16; off <<= 1) {
                const int u = __shfl_up(in2, off);
                if (lane >= off) in2 += u;
            }
            sh.bin.wsum[lane] = in2 - s;    // exclusive wave offset
        }
        __syncthreads();
        if (t < NCELL) {
            const int excl = incl - v + sh.bin.wsum[wid];
            starts[b * (NCELL + 1) + t] = excl;   // consumed next dispatch
            atomicExch(&cursor[b * NCELL + t], excl);  // device-visible NOW
            if (t == NCELL - 1) starts[b * (NCELL + 1) + NCELL] = excl + v;
        }
        __threadfence();                // drain all bin writes (all threads)
        __syncthreads();
        if (t == 0)
            __hip_atomic_store(&flags[b], FLAG_MAGIC, __ATOMIC_RELEASE,
                               __HIP_MEMORY_SCOPE_AGENT);
    }

    // ---- wait for my scatter batch's cursor to be ready -----------------
    if (t == 0) {
        while (__hip_atomic_load(&flags[jb], __ATOMIC_ACQUIRE,
                                 __HIP_MEMORY_SCOPE_AGENT) != FLAG_MAGIC) {
            __builtin_amdgcn_s_sleep(8);
        }
    }
    __syncthreads();                    // broadcast acquire to all threads

    // ---- scatter own 128 points -----------------------------------------
    if (t < 128) {
        const int n = base_n + t;
        const float x = points[(jb * 3 + 0) * N_PTS + n];   // L2-warm
        const float y = points[(jb * 3 + 1) * N_PTS + n];
        const float z = points[(jb * 3 + 2) * N_PTS + n];
        const int pos = atomicAdd(&cursor[jb * NCELL + cell_of(x, y, z)], 1);
        binned[jb * N_PTS + pos] = make_float4(x, y, z, __int_as_float(n));
    }
}

// ---------------------------------------------------------------------------
// Ball query: EXACT R2 form (measured 104.3). One wave per center; 27-cell
// neighborhood; per-wave LDS bitmap restores exact index order; hoisted
// scalar strip bounds; conflict-free bitmap swizzle.
// ---------------------------------------------------------------------------
__global__ __launch_bounds__(256) void ball_query_kernel(
    const float4* __restrict__ binned,   // (B,N) {x,y,z,idx}
    const float* __restrict__ centers,   // (B,3,M)
    const int* __restrict__ starts,      // (B,1001)
    int* __restrict__ idx_out)           // (B,K,M)
{
    const int lane = threadIdx.x & 63;
    const int wid  = threadIdx.x >> 6;
    const int cid  = blockIdx.x * 4 + wid;
    const int b = cid >> 12;
    const int m = cid & (M_CTR - 1);

    const float r2 = (float)(0.1 * 0.1);

    const float cx = centers[(b * 3 + 0) * M_CTR + m];
    const float cy = centers[(b * 3 + 1) * M_CTR + m];
    const float cz = centers[(b * 3 + 2) * M_CTR + m];
    const float c2 = fadd(fadd(fmul(cx, cx), fmul(cy, cy)), fmul(cz, cz));

    __shared__ unsigned bitmap[4][N_PTS / 32];   // 2 KB per wave
    unsigned* bm = bitmap[wid];
#pragma unroll
    for (int j = 0; j < 8; ++j) bm[j * 64 + lane] = 0u;   // conflict-free

    int ci = (int)(cx * 10.0f); ci = ci < 0 ? 0 : (ci > 9 ? 9 : ci);
    int cj = (int)(cy * 10.0f); cj = cj < 0 ? 0 : (cj > 9 ? 9 : cj);
    int ck = (int)(cz * 10.0f); ck = ck < 0 ? 0 : (ck > 9 ? 9 : ck);
    // wave-uniform by construction (one center per wave) -> tell the compiler
    ci = __builtin_amdgcn_readfirstlane(ci);
    cj = __builtin_amdgcn_readfirstlane(cj);
    ck = __builtin_amdgcn_readfirstlane(ck);
    const int i0 = ci > 0 ? ci - 1 : 0;
    const int i1 = ci < 9 ? ci + 1 : 9;
    const int* st = starts + b * (NCELL + 1);
    const float4* __restrict__ bp = binned + b * N_PTS;

    // Hoist all 9 strips' bounds: scalar address -> s_load, all in flight.
    int lo_d[9], hi_d[9];
#pragma unroll
    for (int d = 0; d < 9; ++d) {
        const int jj = cj + (d % 3) - 1;
        const int kk = ck + (d / 3) - 1;
        const bool ok = (jj >= 0) & (jj <= 9) & (kk >= 0) & (kk <= 9);
        const int base = ok ? (kk * CELLS + jj) * CELLS : 0;  // clamp: safe load
        const int lo = st[base + i0];
        const int hi = st[base + i1 + 1];
        lo_d[d] = ok ? lo : 0;
        hi_d[d] = ok ? hi : 0;
    }

#pragma unroll
    for (int d = 0; d < 9; ++d) {
        const int lo = lo_d[d];
        const int hi = hi_d[d];
        for (int s0 = lo; s0 < hi; s0 += 64) {
            const int t = s0 + lane;
            if (t < hi) {
                const float4 p = bp[t];
                if (bq_valid(p.x, p.y, p.z, cx, cy, cz, c2, r2)) {
                    const int n = __float_as_int(p.w);
                    // word w = n>>5 lives at slot (w&7)*64 + (w>>3)
                    atomicOr((int*)&bm[(((n >> 5) & 7) << 6) + (n >> 8)],
                             1 << (n & 31));
                }
            }
        }
    }

    unsigned w[8];
    int cnt = 0;
#pragma unroll
    for (int j = 0; j < 8; ++j) {            // slot j*64+lane == word lane*8+j
        w[j] = bm[j * 64 + lane];
        cnt += __popc(w[j]);
    }

    int incl = cnt;
    for (int off = 1; off < 64; off <<= 1) {
        const int v = __shfl_up(incl, off);
        if (lane >= off) incl += v;
    }
    const int total = __shfl(incl, 63);
    int slot = incl - cnt;

    int firstbit = 0x7fffffff;
#pragma unroll
    for (int j = 0; j < 8; ++j) {
        if (w[j] && firstbit == 0x7fffffff)
            firstbit = lane * 256 + j * 32 + (__ffs(w[j]) - 1);
    }
    for (int off = 32; off > 0; off >>= 1)
        firstbit = min(firstbit, __shfl_xor(firstbit, off));
    const int first_idx = (total == 0) ? 0 : firstbit;

    int* __restrict__ dst = idx_out + (b * K_NB) * M_CTR + m;
#pragma unroll
    for (int j = 0; j < 8; ++j) {
        unsigned x = w[j];
        while (x && slot < K_NB) {
            const int bit = __ffs(x) - 1;
            dst[slot * M_CTR] = lane * 256 + j * 32 + bit;
            x &= x - 1;
            ++slot;
        }
    }
    if (lane >= total && lane < K_NB) dst[lane * M_CTR] = first_idx;
}

// ---------------------------------------------------------------------------
// Gather: EXACT R2 form (measured 104.3). 2 consecutive-m per thread,
// float2 NT plane stores, int2 idx loads.
// ---------------------------------------------------------------------------
__global__ __launch_bounds__(256) void gather_kernel(
    const float* __restrict__ pf,       // (B,N,36)
    const float* __restrict__ centers,  // (B,3,M)
    const int* __restrict__ idx,        // (B,K,M)
    float* __restrict__ out)            // (B,35,K,M)
{
    const int t = blockIdx.x * 256 + threadIdx.x;   // 0..131071
    const int m = (t & (M_CTR / 2 - 1)) * 2;
    const int k = (t >> 11) & (K_NB - 1);
    const int b = t >> 16;

    const int2 nn = *(const int2*)&idx[(b * K_NB + k) * M_CTR + m];
    const float4* __restrict__ s0 =
        (const float4*)(pf + ((size_t)b * N_PTS + nn.x) * 36);
    const float4* __restrict__ s1 =
        (const float4*)(pf + ((size_t)b * N_PTS + nn.y) * 36);

    float4 f0[9], f1[9];
#pragma unroll
    for (int i = 0; i < 9; ++i) { f0[i] = s0[i]; f1[i] = s1[i]; }

    const float2 cx = *(const float2*)&centers[(b * 3 + 0) * M_CTR + m];
    const float2 cy = *(const float2*)&centers[(b * 3 + 1) * M_CTR + m];
    const float2 cz = *(const float2*)&centers[(b * 3 + 2) * M_CTR + m];

    float v0[36], v1[36];
#pragma unroll
    for (int i = 0; i < 9; ++i) {
        v0[4 * i + 0] = f0[i].x; v0[4 * i + 1] = f0[i].y;
        v0[4 * i + 2] = f0[i].z; v0[4 * i + 3] = f0[i].w;
        v1[4 * i + 0] = f1[i].x; v1[4 * i + 1] = f1[i].y;
        v1[4 * i + 2] = f1[i].z; v1[4 * i + 3] = f1[i].w;
    }
    v0[0] -= cx.x; v0[1] -= cy.x; v0[2] -= cz.x;   // single f32 subtract
    v1[0] -= cx.y; v1[1] -= cy.y; v1[2] -= cz.y;

    float* __restrict__ o = out + ((size_t)b * NCH * K_NB + k) * M_CTR + m;
#pragma unroll
    for (int ch = 0; ch < NCH; ++ch) {
        vfloat2 pv; pv.x = v0[ch]; pv.y = v1[ch];
        __builtin_nontemporal_store(pv, (vfloat2*)&o[(size_t)ch * CH_STRIDE]);
    }
}

extern "C" void kernel_launch(void* const* d_in, const int* in_sizes, int n_in,
                              void* d_out, int out_size, void* d_ws, size_t ws_size,
                              hipStream_t stream) {
    const float* points  = (const float*)d_in[0];
    const float* centers = (const float*)d_in[1];
    const float* feats   = (const float*)d_in[2];
    float* out = (float*)d_out;

    char* ws = (char*)d_ws;
    int*    idx    = (int*)ws;                               // 1 MiB
    float*  pf     = (float*)(ws + (1u << 20));              // 4.5 MiB
    int*    cursor = (int*)(ws + 5716 * 1024);               // 8 KB
    int*    starts = (int*)(ws + 5732 * 1024);               // 8 KB
    unsigned long long* flags =
        (unsigned long long*)(ws + 5748 * 1024);             // 16 B
    float4* binned = (float4*)(ws + 5764 * 1024);            // 512 KB

    prep_kernel<<<256, 1024, 0, stream>>>(
        points, feats, starts, cursor, flags, binned, pf);
    ball_query_kernel<<<(B_SZ * M_CTR) / 4, 256, 0, stream>>>(
        binned, centers, starts, idx);
    gather_kernel<<<(B_SZ * K_NB * M_CTR / 2) / 256, 256, 0, stream>>>(
        pf, centers, idx, out);
}

// Round 6
// 100.465 us; speedup vs baseline: 1.7355x; 1.7355x over previous
//
#include <hip/hip_runtime.h>

#define B_SZ  2
#define N_PTS 16384
#define M_CTR 4096
#define C_FT  32
#define K_NB  32
#define NCH   35   // 3 + C_FT
#define CH_STRIDE (K_NB * M_CTR)   // 131072
#define CELLS 10
#define NCELL (CELLS * CELLS * CELLS)
#define NCHUNK 16                  // hist chunks per batch (1024 pts each)

typedef float vfloat2 __attribute__((ext_vector_type(2)));  // NT-store-able

// ---------------------------------------------------------------------------
// Exact single-rounded f32 ops, opaque to the compiler. v_fma_f32 ONLY where
// the numpy golden fuses (einsum cp accumulation). absmax==0.0 since R6 —
// DO NOT change the math.
// ---------------------------------------------------------------------------
__device__ __forceinline__ float fmul(float a, float b) {
    float r; asm("v_mul_f32 %0, %1, %2" : "=v"(r) : "v"(a), "v"(b)); return r;
}
__device__ __forceinline__ float fadd(float a, float b) {
    float r; asm("v_add_f32 %0, %1, %2" : "=v"(r) : "v"(a), "v"(b)); return r;
}
__device__ __forceinline__ float fsub(float a, float b) {
    float r; asm("v_sub_f32 %0, %1, %2" : "=v"(r) : "v"(a), "v"(b)); return r;
}
__device__ __forceinline__ float ffma(float a, float b, float c) {
    float r; asm("v_fma_f32 %0, %1, %2, %3" : "=v"(r) : "v"(a), "v"(b), "v"(c));
    return r;
}

__device__ __forceinline__ bool bq_valid(float x, float y, float z,
                                         float cx, float cy, float cz,
                                         float c2, float r2) {
    const float p2 = fadd(fadd(fmul(x, x), fmul(y, y)), fmul(z, z));
    const float cp = ffma(cz, z, ffma(cy, y, fmul(cx, x)));
    return fsub(fadd(c2, p2), fmul(2.0f, cp)) < r2;
}

__device__ __forceinline__ int cell_of(float x, float y, float z) {
    int ci = (int)(x * 10.0f); ci = ci < 0 ? 0 : (ci > 9 ? 9 : ci);
    int cj = (int)(y * 10.0f); cj = cj < 0 ? 0 : (cj > 9 ? 9 : cj);
    int ck = (int)(z * 10.0f); ck = ck < 0 ? 0 : (ck > 9 ? 9 : ck);
    return (ck * CELLS + cj) * CELLS + ci;   // x fastest
}

// ---------------------------------------------------------------------------
// R15 prep: NO serial bin block, NO sync primitives.
//   blocks 0..255   : transpose 128 pts each (two sequential 64-pt tiles)
//   blocks 256..287 : partial hist — block h: batch h>>4, chunk h&15,
//                     1024 pts -> LDS hist -> plain store ghist[b][q][cell].
// 288 blocks * 16 waves = 4608 waves, all-resident (cap 8192) -> one round.
// Ordering to consumers is the dispatch boundary (R12/R14 lesson: any
// in-kernel ordering primitive loses to a plain boundary on this chip).
// ---------------------------------------------------------------------------
__global__ __launch_bounds__(1024) void prep_kernel(
    const float* __restrict__ points,   // (B,3,N)
    const float* __restrict__ feats,    // (B,C,N)
    int* __restrict__ ghist,            // (B,NCHUNK,NCELL)
    float* __restrict__ pf)             // (B,N,36)
{
    __shared__ union {
        float tile[64][37];             // 9.25 KB (transpose)
        int   h[NCELL];                 // 4 KB   (hist)
    } sh;
    const int t = threadIdx.x;

    if (blockIdx.x < 256) {
        const int jb = blockIdx.x >> 7;            // batch
        const int base_n = (blockIdx.x & 127) * 128;
#pragma unroll
        for (int half = 0; half < 2; ++half) {
            const int n0 = base_n + half * 64;
            if (half) __syncthreads();             // protect prev tile reads
            for (int i = t; i < NCH * 64; i += 1024) {
                const int r = i >> 6;
                const int c = i & 63;
                float v;
                if (r < 3) v = points[(jb * 3 + r) * N_PTS + n0 + c];
                else       v = feats[(jb * C_FT + (r - 3)) * N_PTS + n0 + c];
                sh.tile[c][r] = v;
            }
            if (t < 64) sh.tile[t][35] = 0.0f;
            __syncthreads();
            float* __restrict__ dst = pf + ((size_t)jb * N_PTS + n0) * 36;
            for (int o = t; o < 64 * 36; o += 1024) {
                const int c = o / 36;
                const int r = o - c * 36;
                dst[o] = sh.tile[c][r];
            }
        }
    } else {
        const int hb = blockIdx.x - 256;           // 0..31
        const int b = hb >> 4;
        const int q = hb & (NCHUNK - 1);
        for (int c = t; c < NCELL; c += 1024) sh.h[c] = 0;
        __syncthreads();
        const int n = q * 1024 + t;                // 1 pt/thread
        const float x = points[(b * 3 + 0) * N_PTS + n];
        const float y = points[(b * 3 + 1) * N_PTS + n];
        const float z = points[(b * 3 + 2) * N_PTS + n];
        atomicAdd(&sh.h[cell_of(x, y, z)], 1);
        __syncthreads();
        int* __restrict__ g = ghist + (b * NCHUNK + q) * NCELL;
        for (int c = t; c < NCELL; c += 1024) g[c] = sh.h[c];
    }
}

// ---------------------------------------------------------------------------
// R15 scatter: 32 blocks (16/batch), each owns chunk q (1024 pts).
// Each block REDUNDANTLY computes the global scan from the 16 partial
// hists (parallel redundancy instead of synchronization), derives its
// chunk's deterministic per-cell base (excl[c] + sum of chunks < q), and
// scatters its points with LDS-local rank atomics. Deterministic,
// collision-free; intra-cell order irrelevant (bq bitmap restores global
// index order). Chunk-0 blocks also publish starts for bq.
// ---------------------------------------------------------------------------
__global__ __launch_bounds__(256) void scatter_kernel(
    const float* __restrict__ points,   // (B,3,N)
    const int* __restrict__ ghist,      // (B,NCHUNK,NCELL)
    int* __restrict__ starts,           // (B,1001)
    float4* __restrict__ binned)        // (B,N) {x,y,z,idx}
{
    const int t = threadIdx.x;
    const int lane = t & 63, wid = t >> 6;
    const int b = blockIdx.x >> 4;
    const int q = blockIdx.x & (NCHUNK - 1);

    __shared__ int curs[NCELL];
    __shared__ int wsum[4];

    // per-thread 4 consecutive cells: totals + prefix of chunks < q
    const int c0 = 4 * t;
    int tot[4] = {0, 0, 0, 0};
    int pre[4] = {0, 0, 0, 0};
    if (c0 < NCELL) {
        const int* __restrict__ gb = ghist + b * NCHUNK * NCELL;
#pragma unroll
        for (int qq = 0; qq < NCHUNK; ++qq) {
            const int4 v = *(const int4*)&gb[qq * NCELL + c0];
            tot[0] += v.x; tot[1] += v.y; tot[2] += v.z; tot[3] += v.w;
            if (qq < q) { pre[0] += v.x; pre[1] += v.y;
                          pre[2] += v.z; pre[3] += v.w; }
        }
    }
    const int s = tot[0] + tot[1] + tot[2] + tot[3];
    int incl = s;
    for (int off = 1; off < 64; off <<= 1) {
        const int u = __shfl_up(incl, off);
        if (lane >= off) incl += u;
    }
    if (lane == 63) wsum[wid] = incl;
    __syncthreads();
    if (t == 0) {
        int acc = 0;
        for (int w2 = 0; w2 < 4; ++w2) {
            const int x = wsum[w2]; wsum[w2] = acc; acc += x;
        }
    }
    __syncthreads();
    if (c0 < NCELL) {
        int e = incl - s + wsum[wid];    // global exclusive start of c0
#pragma unroll
        for (int i = 0; i < 4; ++i) {
            if (q == 0) starts[b * (NCELL + 1) + c0 + i] = e;
            curs[c0 + i] = e + pre[i];   // my chunk's base within cell
            e += tot[i];
        }
        if (q == 0 && c0 + 4 == NCELL)
            starts[b * (NCELL + 1) + NCELL] = e;   // = N_PTS
    }
    __syncthreads();

    // scatter my 1024 points (4/thread, coalesced reads)
    const float* __restrict__ px = points + (b * 3 + 0) * N_PTS;
    const float* __restrict__ py = points + (b * 3 + 1) * N_PTS;
    const float* __restrict__ pz = points + (b * 3 + 2) * N_PTS;
    float4* __restrict__ bb = binned + b * N_PTS;
#pragma unroll
    for (int i = 0; i < 4; ++i) {
        const int n = q * 1024 + i * 256 + t;
        const float x = px[n], y = py[n], z = pz[n];
        const int pos = atomicAdd(&curs[cell_of(x, y, z)], 1);
        bb[pos] = make_float4(x, y, z, __int_as_float(n));
    }
}

// ---------------------------------------------------------------------------
// Ball query: EXACT R2 form (measured 104.3). One wave per center; 27-cell
// neighborhood; per-wave LDS bitmap restores exact index order; hoisted
// scalar strip bounds; conflict-free bitmap swizzle.
// ---------------------------------------------------------------------------
__global__ __launch_bounds__(256) void ball_query_kernel(
    const float4* __restrict__ binned,   // (B,N) {x,y,z,idx}
    const float* __restrict__ centers,   // (B,3,M)
    const int* __restrict__ starts,      // (B,1001)
    int* __restrict__ idx_out)           // (B,K,M)
{
    const int lane = threadIdx.x & 63;
    const int wid  = threadIdx.x >> 6;
    const int cid  = blockIdx.x * 4 + wid;
    const int b = cid >> 12;
    const int m = cid & (M_CTR - 1);

    const float r2 = (float)(0.1 * 0.1);

    const float cx = centers[(b * 3 + 0) * M_CTR + m];
    const float cy = centers[(b * 3 + 1) * M_CTR + m];
    const float cz = centers[(b * 3 + 2) * M_CTR + m];
    const float c2 = fadd(fadd(fmul(cx, cx), fmul(cy, cy)), fmul(cz, cz));

    __shared__ unsigned bitmap[4][N_PTS / 32];   // 2 KB per wave
    unsigned* bm = bitmap[wid];
#pragma unroll
    for (int j = 0; j < 8; ++j) bm[j * 64 + lane] = 0u;   // conflict-free

    int ci = (int)(cx * 10.0f); ci = ci < 0 ? 0 : (ci > 9 ? 9 : ci);
    int cj = (int)(cy * 10.0f); cj = cj < 0 ? 0 : (cj > 9 ? 9 : cj);
    int ck = (int)(cz * 10.0f); ck = ck < 0 ? 0 : (ck > 9 ? 9 : ck);
    // wave-uniform by construction (one center per wave) -> tell the compiler
    ci = __builtin_amdgcn_readfirstlane(ci);
    cj = __builtin_amdgcn_readfirstlane(cj);
    ck = __builtin_amdgcn_readfirstlane(ck);
    const int i0 = ci > 0 ? ci - 1 : 0;
    const int i1 = ci < 9 ? ci + 1 : 9;
    const int* st = starts + b * (NCELL + 1);
    const float4* __restrict__ bp = binned + b * N_PTS;

    // Hoist all 9 strips' bounds: scalar address -> s_load, all in flight.
    int lo_d[9], hi_d[9];
#pragma unroll
    for (int d = 0; d < 9; ++d) {
        const int jj = cj + (d % 3) - 1;
        const int kk = ck + (d / 3) - 1;
        const bool ok = (jj >= 0) & (jj <= 9) & (kk >= 0) & (kk <= 9);
        const int base = ok ? (kk * CELLS + jj) * CELLS : 0;  // clamp: safe load
        const int lo = st[base + i0];
        const int hi = st[base + i1 + 1];
        lo_d[d] = ok ? lo : 0;
        hi_d[d] = ok ? hi : 0;
    }

#pragma unroll
    for (int d = 0; d < 9; ++d) {
        const int lo = lo_d[d];
        const int hi = hi_d[d];
        for (int s0 = lo; s0 < hi; s0 += 64) {
            const int t = s0 + lane;
            if (t < hi) {
                const float4 p = bp[t];
                if (bq_valid(p.x, p.y, p.z, cx, cy, cz, c2, r2)) {
                    const int n = __float_as_int(p.w);
                    // word w = n>>5 lives at slot (w&7)*64 + (w>>3)
                    atomicOr((int*)&bm[(((n >> 5) & 7) << 6) + (n >> 8)],
                             1 << (n & 31));
                }
            }
        }
    }

    unsigned w[8];
    int cnt = 0;
#pragma unroll
    for (int j = 0; j < 8; ++j) {            // slot j*64+lane == word lane*8+j
        w[j] = bm[j * 64 + lane];
        cnt += __popc(w[j]);
    }

    int incl = cnt;
    for (int off = 1; off < 64; off <<= 1) {
        const int v = __shfl_up(incl, off);
        if (lane >= off) incl += v;
    }
    const int total = __shfl(incl, 63);
    int slot = incl - cnt;

    int firstbit = 0x7fffffff;
#pragma unroll
    for (int j = 0; j < 8; ++j) {
        if (w[j] && firstbit == 0x7fffffff)
            firstbit = lane * 256 + j * 32 + (__ffs(w[j]) - 1);
    }
    for (int off = 32; off > 0; off >>= 1)
        firstbit = min(firstbit, __shfl_xor(firstbit, off));
    const int first_idx = (total == 0) ? 0 : firstbit;

    int* __restrict__ dst = idx_out + (b * K_NB) * M_CTR + m;
#pragma unroll
    for (int j = 0; j < 8; ++j) {
        unsigned x = w[j];
        while (x && slot < K_NB) {
            const int bit = __ffs(x) - 1;
            dst[slot * M_CTR] = lane * 256 + j * 32 + bit;
            x &= x - 1;
            ++slot;
        }
    }
    if (lane >= total && lane < K_NB) dst[lane * M_CTR] = first_idx;
}

// ---------------------------------------------------------------------------
// Gather: EXACT R2 form (measured 104.3). 2 consecutive-m per thread,
// float2 NT plane stores, int2 idx loads.
// ---------------------------------------------------------------------------
__global__ __launch_bounds__(256) void gather_kernel(
    const float* __restrict__ pf,       // (B,N,36)
    const float* __restrict__ centers,  // (B,3,M)
    const int* __restrict__ idx,        // (B,K,M)
    float* __restrict__ out)            // (B,35,K,M)
{
    const int t = blockIdx.x * 256 + threadIdx.x;   // 0..131071
    const int m = (t & (M_CTR / 2 - 1)) * 2;
    const int k = (t >> 11) & (K_NB - 1);
    const int b = t >> 16;

    const int2 nn = *(const int2*)&idx[(b * K_NB + k) * M_CTR + m];
    const float4* __restrict__ s0 =
        (const float4*)(pf + ((size_t)b * N_PTS + nn.x) * 36);
    const float4* __restrict__ s1 =
        (const float4*)(pf + ((size_t)b * N_PTS + nn.y) * 36);

    float4 f0[9], f1[9];
#pragma unroll
    for (int i = 0; i < 9; ++i) { f0[i] = s0[i]; f1[i] = s1[i]; }

    const float2 cx = *(const float2*)&centers[(b * 3 + 0) * M_CTR + m];
    const float2 cy = *(const float2*)&centers[(b * 3 + 1) * M_CTR + m];
    const float2 cz = *(const float2*)&centers[(b * 3 + 2) * M_CTR + m];

    float v0[36], v1[36];
#pragma unroll
    for (int i = 0; i < 9; ++i) {
        v0[4 * i + 0] = f0[i].x; v0[4 * i + 1] = f0[i].y;
        v0[4 * i + 2] = f0[i].z; v0[4 * i + 3] = f0[i].w;
        v1[4 * i + 0] = f1[i].x; v1[4 * i + 1] = f1[i].y;
        v1[4 * i + 2] = f1[i].z; v1[4 * i + 3] = f1[i].w;
    }
    v0[0] -= cx.x; v0[1] -= cy.x; v0[2] -= cz.x;   // single f32 subtract
    v1[0] -= cx.y; v1[1] -= cy.y; v1[2] -= cz.y;

    float* __restrict__ o = out + ((size_t)b * NCH * K_NB + k) * M_CTR + m;
#pragma unroll
    for (int ch = 0; ch < NCH; ++ch) {
        vfloat2 pv; pv.x = v0[ch]; pv.y = v1[ch];
        __builtin_nontemporal_store(pv, (vfloat2*)&o[(size_t)ch * CH_STRIDE]);
    }
}

extern "C" void kernel_launch(void* const* d_in, const int* in_sizes, int n_in,
                              void* d_out, int out_size, void* d_ws, size_t ws_size,
                              hipStream_t stream) {
    const float* points  = (const float*)d_in[0];
    const float* centers = (const float*)d_in[1];
    const float* feats   = (const float*)d_in[2];
    float* out = (float*)d_out;

    char* ws = (char*)d_ws;
    int*    idx    = (int*)ws;                               // 1 MiB
    float*  pf     = (float*)(ws + (1u << 20));              // 4.5 MiB (ends 5632K)
    int*    ghist  = (int*)(ws + 5636 * 1024);               // 125 KB
    int*    starts = (int*)(ws + 5764 * 1024);               // 8 KB
    float4* binned = (float4*)(ws + 5776 * 1024);            // 512 KB

    prep_kernel<<<256 + B_SZ * NCHUNK, 1024, 0, stream>>>(
        points, feats, ghist, pf);
    scatter_kernel<<<B_SZ * NCHUNK, 256, 0, stream>>>(
        points, ghist, starts, binned);
    ball_query_kernel<<<(B_SZ * M_CTR) / 4, 256, 0, stream>>>(
        binned, centers, starts, idx);
    gather_kernel<<<(B_SZ * K_NB * M_CTR / 2) / 256, 256, 0, stream>>>(
        pf, centers, idx, out);
}

// Round 7
// 98.983 us; speedup vs baseline: 1.7615x; 1.0150x over previous
//
#include <hip/hip_runtime.h>

#define B_SZ  2
#define N_PTS 16384
#define M_CTR 4096
#define C_FT  32
#define K_NB  32
#define NCH   35   // 3 + C_FT
#define CH_STRIDE (K_NB * M_CTR)   // 131072
#define CELLS 10
#define NCELL (CELLS * CELLS * CELLS)
#define NCHUNK 16                  // hist chunks per batch (1024 pts each)
#define BQ_BLOCKS ((B_SZ * M_CTR) / 4)    // 2048
#define TR_BLOCKS ((B_SZ * N_PTS) / 64)   // 512 transpose tiles

typedef float vfloat2 __attribute__((ext_vector_type(2)));  // NT-store-able

// ---------------------------------------------------------------------------
// Exact single-rounded f32 ops, opaque to the compiler. v_fma_f32 ONLY where
// the numpy golden fuses (einsum cp accumulation). absmax==0.0 since R6 —
// DO NOT change the math.
// ---------------------------------------------------------------------------
__device__ __forceinline__ float fmul(float a, float b) {
    float r; asm("v_mul_f32 %0, %1, %2" : "=v"(r) : "v"(a), "v"(b)); return r;
}
__device__ __forceinline__ float fadd(float a, float b) {
    float r; asm("v_add_f32 %0, %1, %2" : "=v"(r) : "v"(a), "v"(b)); return r;
}
__device__ __forceinline__ float fsub(float a, float b) {
    float r; asm("v_sub_f32 %0, %1, %2" : "=v"(r) : "v"(a), "v"(b)); return r;
}
__device__ __forceinline__ float ffma(float a, float b, float c) {
    float r; asm("v_fma_f32 %0, %1, %2, %3" : "=v"(r) : "v"(a), "v"(b), "v"(c));
    return r;
}

__device__ __forceinline__ bool bq_valid(float x, float y, float z,
                                         float cx, float cy, float cz,
                                         float c2, float r2) {
    const float p2 = fadd(fadd(fmul(x, x), fmul(y, y)), fmul(z, z));
    const float cp = ffma(cz, z, ffma(cy, y, fmul(cx, x)));
    return fsub(fadd(c2, p2), fmul(2.0f, cp)) < r2;
}

__device__ __forceinline__ int cell_of(float x, float y, float z) {
    int ci = (int)(x * 10.0f); ci = ci < 0 ? 0 : (ci > 9 ? 9 : ci);
    int cj = (int)(y * 10.0f); cj = cj < 0 ? 0 : (cj > 9 ? 9 : cj);
    int ck = (int)(z * 10.0f); ck = ck < 0 ? 0 : (ck > 9 ? 9 : ck);
    return (ck * CELLS + cj) * CELLS + ci;   // x fastest
}

// ---------------------------------------------------------------------------
// R16 prep: hist-only (transpose moved into the bq dispatch — pf is only
// consumed by gather, so it doesn't belong on the prep->scatter critical
// path). 32 blocks: block h = batch h>>4, chunk h&15; 1024 pts -> LDS hist
// -> plain store ghist[b][q][cell]. Ordering via dispatch boundary.
// ---------------------------------------------------------------------------
__global__ __launch_bounds__(1024) void prep_kernel(
    const float* __restrict__ points,   // (B,3,N)
    int* __restrict__ ghist)            // (B,NCHUNK,NCELL)
{
    __shared__ int h[NCELL];
    const int t = threadIdx.x;
    const int b = blockIdx.x >> 4;
    const int q = blockIdx.x & (NCHUNK - 1);
    for (int c = t; c < NCELL; c += 1024) h[c] = 0;
    __syncthreads();
    const int n = q * 1024 + t;                // 1 pt/thread
    const float x = points[(b * 3 + 0) * N_PTS + n];
    const float y = points[(b * 3 + 1) * N_PTS + n];
    const float z = points[(b * 3 + 2) * N_PTS + n];
    atomicAdd(&h[cell_of(x, y, z)], 1);
    __syncthreads();
    int* __restrict__ g = ghist + (b * NCHUNK + q) * NCELL;
    for (int c = t; c < NCELL; c += 1024) g[c] = h[c];
}

// ---------------------------------------------------------------------------
// R15 scatter (unchanged, measured in the 100.5 pipeline): 32 blocks
// (16/batch), each owns chunk q (1024 pts). Each block REDUNDANTLY computes
// the global scan from the 16 partial hists, derives its chunk's
// deterministic per-cell base, scatters with LDS-local rank atomics.
// Chunk-0 blocks publish starts for bq.
// ---------------------------------------------------------------------------
__global__ __launch_bounds__(256) void scatter_kernel(
    const float* __restrict__ points,   // (B,3,N)
    const int* __restrict__ ghist,      // (B,NCHUNK,NCELL)
    int* __restrict__ starts,           // (B,1001)
    float4* __restrict__ binned)        // (B,N) {x,y,z,idx}
{
    const int t = threadIdx.x;
    const int lane = t & 63, wid = t >> 6;
    const int b = blockIdx.x >> 4;
    const int q = blockIdx.x & (NCHUNK - 1);

    __shared__ int curs[NCELL];
    __shared__ int wsum[4];

    // per-thread 4 consecutive cells: totals + prefix of chunks < q
    const int c0 = 4 * t;
    int tot[4] = {0, 0, 0, 0};
    int pre[4] = {0, 0, 0, 0};
    if (c0 < NCELL) {
        const int* __restrict__ gb = ghist + b * NCHUNK * NCELL;
#pragma unroll
        for (int qq = 0; qq < NCHUNK; ++qq) {
            const int4 v = *(const int4*)&gb[qq * NCELL + c0];
            tot[0] += v.x; tot[1] += v.y; tot[2] += v.z; tot[3] += v.w;
            if (qq < q) { pre[0] += v.x; pre[1] += v.y;
                          pre[2] += v.z; pre[3] += v.w; }
        }
    }
    const int s = tot[0] + tot[1] + tot[2] + tot[3];
    int incl = s;
    for (int off = 1; off < 64; off <<= 1) {
        const int u = __shfl_up(incl, off);
        if (lane >= off) incl += u;
    }
    if (lane == 63) wsum[wid] = incl;
    __syncthreads();
    if (t == 0) {
        int acc = 0;
        for (int w2 = 0; w2 < 4; ++w2) {
            const int x = wsum[w2]; wsum[w2] = acc; acc += x;
        }
    }
    __syncthreads();
    if (c0 < NCELL) {
        int e = incl - s + wsum[wid];    // global exclusive start of c0
#pragma unroll
        for (int i = 0; i < 4; ++i) {
            if (q == 0) starts[b * (NCELL + 1) + c0 + i] = e;
            curs[c0 + i] = e + pre[i];   // my chunk's base within cell
            e += tot[i];
        }
        if (q == 0 && c0 + 4 == NCELL)
            starts[b * (NCELL + 1) + NCELL] = e;   // = N_PTS
    }
    __syncthreads();

    // scatter my 1024 points (4/thread, coalesced reads)
    const float* __restrict__ px = points + (b * 3 + 0) * N_PTS;
    const float* __restrict__ py = points + (b * 3 + 1) * N_PTS;
    const float* __restrict__ pz = points + (b * 3 + 2) * N_PTS;
    float4* __restrict__ bb = binned + b * N_PTS;
#pragma unroll
    for (int i = 0; i < 4; ++i) {
        const int n = q * 1024 + i * 256 + t;
        const float x = px[n], y = py[n], z = pz[n];
        const int pos = atomicAdd(&curs[cell_of(x, y, z)], 1);
        bb[pos] = make_float4(x, y, z, __int_as_float(n));
    }
}

// ---------------------------------------------------------------------------
// Ball query + transpose, one dispatch.
//   blocks 0..2047    : EXACT R2 bq form (measured). One wave per center;
//                       27-cell neighborhood; per-wave LDS bitmap restores
//                       exact index order; hoisted scalar strip bounds;
//                       conflict-free bitmap swizzle.
//   blocks 2048..2559 : transpose one 64-pt tile -> pf (R16: moved here
//                       from prep — pf is consumed only by gather, so the
//                       transpose runs in bq's shadow instead of extending
//                       the prep->scatter critical path).
// LDS: union of bitmap (8 KB) and tile (9.25 KB).
// ---------------------------------------------------------------------------
__global__ __launch_bounds__(256) void ball_query_kernel(
    const float4* __restrict__ binned,   // (B,N) {x,y,z,idx}
    const float* __restrict__ centers,   // (B,3,M)
    const int* __restrict__ starts,      // (B,1001)
    const float* __restrict__ points,    // (B,3,N)   [transpose role]
    const float* __restrict__ feats,     // (B,C,N)   [transpose role]
    float* __restrict__ pf,              // (B,N,36)  [transpose role]
    int* __restrict__ idx_out)           // (B,K,M)
{
    __shared__ union {
        unsigned bitmap[4][N_PTS / 32];  // 8 KB   (bq role)
        float    tile[64][37];           // 9.25 KB (transpose role)
    } sh;
    const int t = threadIdx.x;

    if (blockIdx.x >= BQ_BLOCKS) {
        // ---- transpose role ------------------------------------------------
        const int tid = blockIdx.x - BQ_BLOCKS;   // 0..511
        const int jb = tid >> 8;                  // batch
        const int n0 = (tid & 255) * 64;
        for (int i = t; i < NCH * 64; i += 256) {
            const int r = i >> 6;
            const int c = i & 63;
            float v;
            if (r < 3) v = points[(jb * 3 + r) * N_PTS + n0 + c];
            else       v = feats[(jb * C_FT + (r - 3)) * N_PTS + n0 + c];
            sh.tile[c][r] = v;
        }
        if (t < 64) sh.tile[t][35] = 0.0f;
        __syncthreads();
        float* __restrict__ dst = pf + ((size_t)jb * N_PTS + n0) * 36;
        for (int o = t; o < 64 * 36; o += 256) {
            const int c = o / 36;
            const int r = o - c * 36;
            dst[o] = sh.tile[c][r];
        }
        return;
    }

    // ---- bq role -----------------------------------------------------------
    const int lane = t & 63;
    const int wid  = t >> 6;
    const int cid  = blockIdx.x * 4 + wid;
    const int b = cid >> 12;
    const int m = cid & (M_CTR - 1);

    const float r2 = (float)(0.1 * 0.1);

    const float cx = centers[(b * 3 + 0) * M_CTR + m];
    const float cy = centers[(b * 3 + 1) * M_CTR + m];
    const float cz = centers[(b * 3 + 2) * M_CTR + m];
    const float c2 = fadd(fadd(fmul(cx, cx), fmul(cy, cy)), fmul(cz, cz));

    unsigned* bm = sh.bitmap[wid];
#pragma unroll
    for (int j = 0; j < 8; ++j) bm[j * 64 + lane] = 0u;   // conflict-free

    int ci = (int)(cx * 10.0f); ci = ci < 0 ? 0 : (ci > 9 ? 9 : ci);
    int cj = (int)(cy * 10.0f); cj = cj < 0 ? 0 : (cj > 9 ? 9 : cj);
    int ck = (int)(cz * 10.0f); ck = ck < 0 ? 0 : (ck > 9 ? 9 : ck);
    // wave-uniform by construction (one center per wave) -> tell the compiler
    ci = __builtin_amdgcn_readfirstlane(ci);
    cj = __builtin_amdgcn_readfirstlane(cj);
    ck = __builtin_amdgcn_readfirstlane(ck);
    const int i0 = ci > 0 ? ci - 1 : 0;
    const int i1 = ci < 9 ? ci + 1 : 9;
    const int* st = starts + b * (NCELL + 1);
    const float4* __restrict__ bp = binned + b * N_PTS;

    // Hoist all 9 strips' bounds: scalar address -> s_load, all in flight.
    int lo_d[9], hi_d[9];
#pragma unroll
    for (int d = 0; d < 9; ++d) {
        const int jj = cj + (d % 3) - 1;
        const int kk = ck + (d / 3) - 1;
        const bool ok = (jj >= 0) & (jj <= 9) & (kk >= 0) & (kk <= 9);
        const int base = ok ? (kk * CELLS + jj) * CELLS : 0;  // clamp: safe load
        const int lo = st[base + i0];
        const int hi = st[base + i1 + 1];
        lo_d[d] = ok ? lo : 0;
        hi_d[d] = ok ? hi : 0;
    }

#pragma unroll
    for (int d = 0; d < 9; ++d) {
        const int lo = lo_d[d];
        const int hi = hi_d[d];
        for (int s0 = lo; s0 < hi; s0 += 64) {
            const int tt = s0 + lane;
            if (tt < hi) {
                const float4 p = bp[tt];
                if (bq_valid(p.x, p.y, p.z, cx, cy, cz, c2, r2)) {
                    const int n = __float_as_int(p.w);
                    // word w = n>>5 lives at slot (w&7)*64 + (w>>3)
                    atomicOr((int*)&bm[(((n >> 5) & 7) << 6) + (n >> 8)],
                             1 << (n & 31));
                }
            }
        }
    }

    unsigned w[8];
    int cnt = 0;
#pragma unroll
    for (int j = 0; j < 8; ++j) {            // slot j*64+lane == word lane*8+j
        w[j] = bm[j * 64 + lane];
        cnt += __popc(w[j]);
    }

    int incl = cnt;
    for (int off = 1; off < 64; off <<= 1) {
        const int v = __shfl_up(incl, off);
        if (lane >= off) incl += v;
    }
    const int total = __shfl(incl, 63);
    int slot = incl - cnt;

    int firstbit = 0x7fffffff;
#pragma unroll
    for (int j = 0; j < 8; ++j) {
        if (w[j] && firstbit == 0x7fffffff)
            firstbit = lane * 256 + j * 32 + (__ffs(w[j]) - 1);
    }
    for (int off = 32; off > 0; off >>= 1)
        firstbit = min(firstbit, __shfl_xor(firstbit, off));
    const int first_idx = (total == 0) ? 0 : firstbit;

    int* __restrict__ dst = idx_out + (b * K_NB) * M_CTR + m;
#pragma unroll
    for (int j = 0; j < 8; ++j) {
        unsigned x = w[j];
        while (x && slot < K_NB) {
            const int bit = __ffs(x) - 1;
            dst[slot * M_CTR] = lane * 256 + j * 32 + bit;
            x &= x - 1;
            ++slot;
        }
    }
    if (lane >= total && lane < K_NB) dst[lane * M_CTR] = first_idx;
}

// ---------------------------------------------------------------------------
// Gather: EXACT R2 form (measured). 2 consecutive-m per thread, float2 NT
// plane stores, int2 idx loads.
// ---------------------------------------------------------------------------
__global__ __launch_bounds__(256) void gather_kernel(
    const float* __restrict__ pf,       // (B,N,36)
    const float* __restrict__ centers,  // (B,3,M)
    const int* __restrict__ idx,        // (B,K,M)
    float* __restrict__ out)            // (B,35,K,M)
{
    const int t = blockIdx.x * 256 + threadIdx.x;   // 0..131071
    const int m = (t & (M_CTR / 2 - 1)) * 2;
    const int k = (t >> 11) & (K_NB - 1);
    const int b = t >> 16;

    const int2 nn = *(const int2*)&idx[(b * K_NB + k) * M_CTR + m];
    const float4* __restrict__ s0 =
        (const float4*)(pf + ((size_t)b * N_PTS + nn.x) * 36);
    const float4* __restrict__ s1 =
        (const float4*)(pf + ((size_t)b * N_PTS + nn.y) * 36);

    float4 f0[9], f1[9];
#pragma unroll
    for (int i = 0; i < 9; ++i) { f0[i] = s0[i]; f1[i] = s1[i]; }

    const float2 cx = *(const float2*)&centers[(b * 3 + 0) * M_CTR + m];
    const float2 cy = *(const float2*)&centers[(b * 3 + 1) * M_CTR + m];
    const float2 cz = *(const float2*)&centers[(b * 3 + 2) * M_CTR + m];

    float v0[36], v1[36];
#pragma unroll
    for (int i = 0; i < 9; ++i) {
        v0[4 * i + 0] = f0[i].x; v0[4 * i + 1] = f0[i].y;
        v0[4 * i + 2] = f0[i].z; v0[4 * i + 3] = f0[i].w;
        v1[4 * i + 0] = f1[i].x; v1[4 * i + 1] = f1[i].y;
        v1[4 * i + 2] = f1[i].z; v1[4 * i + 3] = f1[i].w;
    }
    v0[0] -= cx.x; v0[1] -= cy.x; v0[2] -= cz.x;   // single f32 subtract
    v1[0] -= cx.y; v1[1] -= cy.y; v1[2] -= cz.y;

    float* __restrict__ o = out + ((size_t)b * NCH * K_NB + k) * M_CTR + m;
#pragma unroll
    for (int ch = 0; ch < NCH; ++ch) {
        vfloat2 pv; pv.x = v0[ch]; pv.y = v1[ch];
        __builtin_nontemporal_store(pv, (vfloat2*)&o[(size_t)ch * CH_STRIDE]);
    }
}

extern "C" void kernel_launch(void* const* d_in, const int* in_sizes, int n_in,
                              void* d_out, int out_size, void* d_ws, size_t ws_size,
                              hipStream_t stream) {
    const float* points  = (const float*)d_in[0];
    const float* centers = (const float*)d_in[1];
    const float* feats   = (const float*)d_in[2];
    float* out = (float*)d_out;

    char* ws = (char*)d_ws;
    int*    idx    = (int*)ws;                               // 1 MiB
    float*  pf     = (float*)(ws + (1u << 20));              // 4.5 MiB (ends 5632K)
    int*    ghist  = (int*)(ws + 5636 * 1024);               // 125 KB
    int*    starts = (int*)(ws + 5764 * 1024);               // 8 KB
    float4* binned = (float4*)(ws + 5776 * 1024);            // 512 KB

    prep_kernel<<<B_SZ * NCHUNK, 1024, 0, stream>>>(points, ghist);
    scatter_kernel<<<B_SZ * NCHUNK, 256, 0, stream>>>(
        points, ghist, starts, binned);
    ball_query_kernel<<<BQ_BLOCKS + TR_BLOCKS, 256, 0, stream>>>(
        binned, centers, starts, points, feats, pf, idx);
    gather_kernel<<<(B_SZ * K_NB * M_CTR / 2) / 256, 256, 0, stream>>>(
        pf, centers, idx, out);
}